// Round 10
// baseline (92.102 us; speedup 1.0000x reference)
//
#include <hip/hip_runtime.h>
#include <hip/hip_bf16.h>
#include <hip/hip_fp16.h>

typedef __attribute__((ext_vector_type(8))) _Float16 h16x8;
typedef __attribute__((ext_vector_type(4))) short short4v;
typedef __attribute__((ext_vector_type(2))) short short2v;
typedef __attribute__((ext_vector_type(4))) float f32x4;
typedef __attribute__((ext_vector_type(2))) _Float16 halfx2;

#define C_2PI_8192 7.6699039394282072e-4f

// f16 bit-pattern of v (all GEMM operands are fp16 now: 10-bit mantissa
// cuts GEMM rounding ~8x vs bf16 at identical MFMA rate).
static __device__ __forceinline__ short f16bits(float v) {
  _Float16 h = (_Float16)v;
  return *reinterpret_cast<short*>(&h);
}

#define GLOAD(gp, lp)                                                          \
  __builtin_amdgcn_global_load_lds(                                            \
      (const __attribute__((address_space(1))) void*)(gp),                     \
      (__attribute__((address_space(3))) void*)(lp), 16, 0, 0)

// Decentralized mask-mode detect: byte-bools ~75% nonzero vs int32 ~18.75%.
#define DETECT_BYTEMODE(mask, tid, outvar)                                     \
  __shared__ int _cnt;                                                         \
  if ((tid) == 0) _cnt = 0;                                                    \
  __syncthreads();                                                             \
  {                                                                            \
    const unsigned char* _mb = (const unsigned char*)(mask);                   \
    int _c = 0;                                                                \
    _Pragma("unroll")                                                          \
    for (int _i = 0; _i < 16; ++_i) _c += (_mb[(tid) * 16 + _i] != 0) ? 1 : 0; \
    atomicAdd(&_cnt, _c);                                                      \
  }                                                                            \
  __syncthreads();                                                             \
  const bool outvar = (_cnt > 2048);

static __device__ __forceinline__ float mask_w(const void* mask, bool bytemode, int e) {
  if (bytemode) return (((const unsigned char*)mask)[e] != 0) ? 1.f : 0.f;
  return (((const int*)mask)[e] != 0) ? 1.f : 0.f;
}

// ---------------- K1: build basis tables + f=4095 replica prep + tau/scal + dm
// blocks [0,4096): basis build; [4096,4100): per-b f32-replica (delta, invA);
// [4100,6148): tau/scal (m in [1,2048]); [6148,8196): dm even/odd split.
__global__ __launch_bounds__(256) void k_pre(const void* __restrict__ mask,
                                             const float* __restrict__ data,
                                             short* __restrict__ AE,
                                             short* __restrict__ Be,
                                             short* __restrict__ dmE,
                                             float4* __restrict__ scal,
                                             float* __restrict__ delta,
                                             float* __restrict__ invA) {
  int bid = blockIdx.x, tid = threadIdx.x;
  if (bid < 4096) {
    // ---- basis build (rotation recurrence: 2 trans + 7 rotations), f16 ----
    int region = bid >> 10;
    int idx = (bid & 1023) * 256 + tid;
    short4v lo, hi;
    if (region < 2) {
      // AE/AO: [4096][512], row r: m=(r&2047)+1, sin if r<2048; tau=2(j+1) / 2j+1
      int r = idx >> 6, j8 = (idx & 63) << 3;
      int m = (r & 2047) + 1;
      bool is_sin = (r < 2048);
      int ph0 = (region == 0) ? ((m * (2 * j8 + 2)) & 8191) : ((m * (2 * j8 + 1)) & 8191);
      int step = (2 * m) & 8191;
      float s = __sinf(ph0 * C_2PI_8192), c = __cosf(ph0 * C_2PI_8192);
      float sr = __sinf(step * C_2PI_8192), cr = __cosf(step * C_2PI_8192);
#pragma unroll
      for (int j = 0; j < 8; ++j) {
        float v = is_sin ? s : c;
        if (j < 4) lo[j] = f16bits(v); else hi[j - 4] = f16bits(v);
        float ns = s * cr + c * sr;
        c = c * cr - s * sr;
        s = ns;
      }
      short* dst = AE + (size_t)region * 2097152 + ((size_t)r << 9) + j8;
      *(short4v*)dst = lo;
      *(short4v*)(dst + 4) = hi;
    } else {
      // Be/Bo: [512][4096], row j: tau=2j+2 / 2j+1
      int jr = idx >> 9, k8 = (idx & 511) << 3;
      int tau = (region == 2) ? (2 * jr + 2) : (2 * jr + 1);
      int m0 = (k8 & 2047) + 1;
      bool is_sin = (k8 < 2048);
      int ph0 = (m0 * tau) & 8191;
      float s = __sinf(ph0 * C_2PI_8192), c = __cosf(ph0 * C_2PI_8192);
      float sr = __sinf(tau * C_2PI_8192), cr = __cosf(tau * C_2PI_8192);
#pragma unroll
      for (int j = 0; j < 8; ++j) {
        float v = is_sin ? s : c;
        if (j < 4) lo[j] = f16bits(v); else hi[j - 4] = f16bits(v);
        float ns = s * cr + c * sr;
        c = c * cr - s * sr;
        s = ns;
      }
      short* dst = Be + (size_t)(region - 2) * 2097152 + ((size_t)jr << 12) + k8;
      *(short4v*)dst = lo;
      *(short4v*)(dst + 4) = hi;
    }
    return;
  }
  DETECT_BYTEMODE(mask, tid, bytemode)
  int wid = tid >> 6, lane = tid & 63;
  if (bid < 4100) {
    // ---- f=4095 (m=4096) sin replica: reference f32 arithmetic (accurate sinf!)
    int b = bid - 4096;
    int base_b = b << 10;
    const float W = (float)(6.283185307179586 / 8192.0);
    const float ang = W * 4096.0f;
    __shared__ float red[4][2];
    __shared__ float bc2[1];
    float num = 0.f, den = 0.f;
    for (int t = tid; t < 1024; t += 256) {
      float arg = ang * (float)(t + 1);
      float w = mask_w(mask, bytemode, base_b + t);
      num += w * sinf(2.0f * arg);
      den += w * cosf(2.0f * arg);
    }
#pragma unroll
    for (int m = 32; m; m >>= 1) {
      num += __shfl_xor(num, m, 64);
      den += __shfl_xor(den, m, 64);
    }
    if (lane == 0) { red[wid][0] = num; red[wid][1] = den; }
    __syncthreads();
    if (tid == 0) {
      float a0 = red[0][0] + red[1][0] + red[2][0] + red[3][0];
      float a1 = red[0][1] + red[1][1] + red[2][1] + red[3][1];
      float tau = atan2f(a0, a1) / (2.0f * ang);
      bc2[0] = ang * tau;
    }
    __syncthreads();
    float P = bc2[0];
    float dss = 0.f;
    for (int t = tid; t < 1024; t += 256) {
      float arg = ang * (float)(t + 1);
      float d = sinf(arg - P);
      delta[base_b + t] = d;
      float w = mask_w(mask, bytemode, base_b + t);
      dss += w * d * d;
    }
#pragma unroll
    for (int m = 32; m; m >>= 1) dss += __shfl_xor(dss, m, 64);
    if (lane == 0) red[wid][0] = dss;
    __syncthreads();
    if (tid == 0)
      invA[b] = 1.f / (red[0][0] + red[1][0] + red[2][0] + red[3][0]);
  } else if (bid < 6148) {
    // ---- tau/scal for m in [1,2048]: one wave per (b,f), rotation recurrence ----
    int gw = (bid - 4100) * 4 + wid;
    int b = gw >> 11, f = gw & 2047;
    int base_b = b << 10;
    float num = 0.f, den = 0.f, nb = 0.f;
    int f2 = 2 * (f + 1);
    {
      int ph0 = (f2 * (lane + 1)) & 8191;
      int st = (f2 << 6) & 8191;
      float s = __sinf(ph0 * C_2PI_8192), c = __cosf(ph0 * C_2PI_8192);
      float sr = __sinf(st * C_2PI_8192), cr = __cosf(st * C_2PI_8192);
#pragma unroll
      for (int i = 0; i < 16; ++i) {
        float w = mask_w(mask, bytemode, base_b + lane + (i << 6));
        num += w * s;
        den += w * c;
        nb += w;
        float ns = s * cr + c * sr;
        c = c * cr - s * sr;
        s = ns;
      }
    }
#pragma unroll
    for (int m = 32; m; m >>= 1) {
      num += __shfl_xor(num, m, 64);
      den += __shfl_xor(den, m, 64);
      nb += __shfl_xor(nb, m, 64);
    }
    if (lane == 0) {
      float th = 0.5f * atan2f(num, den);
      float c = cosf(th), s = sinf(th);
      float WSS = 0.5f * (nb - den);
      float WCC = 0.5f * (nb + den);
      float WSC = 0.5f * num;
      float den_s = c * c * WSS - 2.f * c * s * WSC + s * s * WCC;
      float den_c = c * c * WCC + 2.f * c * s * WSC + s * s * WSS;
      scal[gw] = make_float4(c, s, 1.f / den_s, 1.f / den_c);
    }
  } else {
    // ---- dm even/odd-tau split (f16) ----
    int bc = bid - 6148, b = bc >> 9;
    short* dmO = dmE + (1 << 20);
    size_t base = (size_t)bc * 1024 + tid * 4;
    float4 d4 = *(const float4*)(data + base);
    const float* d = (const float*)&d4;
    int me = (b << 10) + tid * 4;
    float wd[4];
#pragma unroll
    for (int j = 0; j < 4; ++j) wd[j] = mask_w(mask, bytemode, me + j) * d[j];
    // t even -> tau odd -> dmO[t/2]; t odd -> tau even -> dmE[(t-1)/2]
    short2v dE, dO;
    dO[0] = f16bits(wd[0]); dE[0] = f16bits(wd[1]);
    dO[1] = f16bits(wd[2]); dE[1] = f16bits(wd[3]);
    *(short2v*)(dmE + (size_t)bc * 512 + tid * 2) = dE;
    *(short2v*)(dmO + (size_t)bc * 512 + tid * 2) = dO;
  }
}

// ---------------- GEMM1 dual (U=even-tau, V=odd-tau) + butterfly-PQ epilogue --
// 512 threads, 8 waves (2M x 4N), per-wave 64x32 output, acc[4][2] x2. fp16 MFMA.
__global__ __launch_bounds__(512, 4) void k_gemm1_pq(const short* __restrict__ dmE,
                                                     const short* __restrict__ AE,
                                                     const float4* __restrict__ scal,
                                                     short* __restrict__ PQe,
                                                     short* __restrict__ PQo) {
  __shared__ short As[128 * 64];
  __shared__ short Bs[128 * 64];
  int bid = blockIdx.x;
  int swz = ((bid & 7) << 6) | (bid >> 3);  // 512 blocks, bijective
  int mt = swz & 15, ft = swz >> 4;          // ft in [0,32)
  int m0 = mt << 7, f0 = ft << 6;
  int tid = threadIdx.x, lane = tid & 63, wid = tid >> 6;
  int wm = (wid >> 2) << 6, wn = (wid & 3) << 5;
  int fr = lane & 15, kh = lane >> 4;

  int r0 = tid >> 3;                          // rows 0-63 per GLOAD wave-set
  int scol = ((tid & 7) ^ (r0 & 7)) << 3;
  const short* pa0 = dmE + (size_t)(m0 + r0) * 512 + scol;
  const short* pb0;
  const short* pb1;
  {
    int row0 = r0, row1 = 64 + r0;
    int g0 = ((row0 >> 4) & 1) * 2048 + f0 + (row0 & 15) + ((row0 >> 5) << 4);
    int g1 = ((row1 >> 4) & 1) * 2048 + f0 + (row1 & 15) + ((row1 >> 5) << 4);
    pb0 = AE + (size_t)g0 * 512 + scol;
    pb1 = AE + (size_t)g1 * 512 + scol;
  }
  char* lA = (char*)As + (wid << 10);
  char* lB = (char*)Bs + (wid << 10);

  f32x4 accU[4][2] = {};
  f32x4 accV[4][2] = {};
  int sw = fr & 7;

#define K_BODY(ACC)                                                              \
  for (int kt = 0; kt < 8; ++kt) {                                               \
    GLOAD(pa0, lA);                                                              \
    GLOAD(pa0 + 32768, lA + 8192);                                               \
    GLOAD(pb0, lB);                                                              \
    GLOAD(pb1, lB + 8192);                                                       \
    pa0 += 64; pb0 += 64; pb1 += 64;                                             \
    __syncthreads();                                                             \
    _Pragma("unroll")                                                            \
    for (int s = 0; s < 2; ++s) {                                                \
      h16x8 a[4];                                                                \
      _Pragma("unroll")                                                          \
      for (int i = 0; i < 4; ++i)                                                \
        a[i] = *(const h16x8*)&As[(wm + i * 16 + fr) * 64 + ((((s << 2) + kh) ^ sw) << 3)]; \
      _Pragma("unroll")                                                          \
      for (int j = 0; j < 2; ++j) {                                              \
        h16x8 bb = *(const h16x8*)&Bs[(wn + j * 16 + fr) * 64 + ((((s << 2) + kh) ^ sw) << 3)]; \
        _Pragma("unroll")                                                        \
        for (int i = 0; i < 4; ++i)                                              \
          ACC[i][j] = __builtin_amdgcn_mfma_f32_16x16x32_f16(a[i], bb, ACC[i][j], 0, 0, 0); \
      }                                                                          \
    }                                                                            \
    __syncthreads();                                                             \
  }

  K_BODY(accU)
  pa0 += (1 << 20) - 512;                    // dmO = dmE + 1M elems
  pb0 += (2 << 20) - 512;                    // AO = AE + 2M elems
  pb1 += (2 << 20) - 512;
  K_BODY(accV)
#undef K_BODY

  int b = m0 >> 9;
  {
    int f = f0 + (wn >> 1) + fr;             // 16 f's per wave
    float4 sc = scal[(b << 11) + f];
    float c = sc.x, s = sc.y, ids = sc.z, idc = sc.w;
    bool self = (f == 2047);                 // m=2048 pairs with itself
#pragma unroll
    for (int i = 0; i < 4; ++i) {
#pragma unroll
      for (int q = 0; q < 4; ++q) {
        int bc = m0 + wm + i * 16 + (kh << 2) + q;
        float US = accU[i][0][q], UC = accU[i][1][q];
        float VS = accV[i][0][q], VC = accV[i][1][q];
        float Gs = US + VS, Gc = UC + VC;      // freq m
        float gs = VS - US, gc = UC - VC;      // freq 4096-m
        float ss = (c * Gs - s * Gc) * ids;
        float cs = (c * Gc + s * Gs) * idc;
        float P = c * ss + s * cs;
        float Q = c * cs - s * ss;
        float ssp = (c * gs + s * gc) * ids;   // partner scal: (c,-s,ids,idc)
        float csp = (c * gc - s * gs) * idc;
        float Pp = self ? 0.f : (c * ssp - s * csp);
        float Qp = self ? 0.f : (c * csp + s * ssp);
        size_t base = (size_t)bc * 4096 + f;
        PQe[base] = f16bits(P - Pp);
        PQe[base + 2048] = f16bits(Q + Qp);
        PQo[base] = f16bits(P + Pp);
        PQo[base + 2048] = f16bits(Q - Qp);
      }
    }
  }
}

// ---------------- GEMM2 (NT, eo x split-K=4, fp16 partials), 512 threads ------
__global__ __launch_bounds__(512, 4) void k_gemm2(const short* __restrict__ PQe,
                                                  const short* __restrict__ Be,
                                                  _Float16* __restrict__ Pe) {
  __shared__ short As[128 * 64];
  __shared__ short Bs[128 * 64];
  int bid = blockIdx.x;
  int swz = ((bid & 7) << 6) | (bid >> 3);  // 512 blocks, bijective
  int eo = swz >> 8;
  int slice = (swz >> 6) & 3;
  int tl = swz & 63;
  int mt = tl & 15, nt = tl >> 4;
  int m0 = mt << 7, n0 = nt << 7;
  int tid = threadIdx.x, lane = tid & 63, wid = tid >> 6;
  int wm = (wid >> 2) << 6, wn = (wid & 3) << 5;
  int fr = lane & 15, kh = lane >> 4;

  const short* A = PQe + (size_t)eo * (8 << 20);
  const short* B = Be + (size_t)eo * (2 << 20);
  _Float16* C = Pe + (size_t)eo * (8 << 20);

  int r0 = tid >> 3;
  int scol = ((tid & 7) ^ (r0 & 7)) << 3;
  const short* pa0 = A + (size_t)slice * 1024 + (size_t)(m0 + r0) * 4096 + scol;
  const short* pb0 = B + (size_t)slice * 1024 + (size_t)(n0 + r0) * 4096 + scol;
  _Float16* Cp = C + (size_t)slice * 1048576;
  char* lA = (char*)As + (wid << 10);
  char* lB = (char*)Bs + (wid << 10);

  f32x4 acc[4][2] = {};
  int sw = fr & 7;

  for (int kt = 0; kt < 16; ++kt) {
    GLOAD(pa0, lA);
    GLOAD(pa0 + 262144, lA + 8192);
    GLOAD(pb0, lB);
    GLOAD(pb0 + 262144, lB + 8192);
    pa0 += 64; pb0 += 64;
    __syncthreads();
#pragma unroll
    for (int s = 0; s < 2; ++s) {
      h16x8 a[4];
#pragma unroll
      for (int i = 0; i < 4; ++i)
        a[i] = *(const h16x8*)&As[(wm + i * 16 + fr) * 64 + ((((s << 2) + kh) ^ sw) << 3)];
#pragma unroll
      for (int j = 0; j < 2; ++j) {
        h16x8 bb = *(const h16x8*)&Bs[(wn + j * 16 + fr) * 64 + ((((s << 2) + kh) ^ sw) << 3)];
#pragma unroll
        for (int i = 0; i < 4; ++i)
          acc[i][j] = __builtin_amdgcn_mfma_f32_16x16x32_f16(a[i], bb, acc[i][j], 0, 0, 0);
      }
    }
    __syncthreads();
  }
#pragma unroll
  for (int i = 0; i < 4; ++i) {
#pragma unroll
    for (int q = 0; q < 4; ++q) {
      size_t row = m0 + wm + i * 16 + (kh << 2) + q;
      _Float16* cp = Cp + row * 512 + n0 + wn + fr;
#pragma unroll
      for (int j = 0; j < 2; ++j) cp[j * 16] = (_Float16)acc[i][j][q];
    }
  }
}

// ---------------- K-tail: merge partials + all per-bc stats + final select ----
__global__ __launch_bounds__(256) void k_tail(const _Float16* __restrict__ Pe,
                                              const _Float16* __restrict__ Po,
                                              const float* __restrict__ data,
                                              const void* __restrict__ mask,
                                              const float* __restrict__ delta,
                                              const float* __restrict__ invA,
                                              float* __restrict__ out) {
  int bc = blockIdx.x, b = bc >> 9, tid = threadIdx.x;
  DETECT_BYTEMODE(mask, tid, bytemode)
  int wid = tid >> 6, lane = tid & 63;
  size_t base = (size_t)bc * 1024 + tid * 4;
  int jj = tid * 2;
  float r[4] = {0.f, 0.f, 0.f, 0.f};
#pragma unroll
  for (int s = 0; s < 4; ++s) {
    halfx2 pe = *(const halfx2*)(Pe + (size_t)s * 1048576 + (size_t)bc * 512 + jj);
    halfx2 po = *(const halfx2*)(Po + (size_t)s * 1048576 + (size_t)bc * 512 + jj);
    r[0] += (float)po[0];  // t even -> tau odd -> Ro
    r[1] += (float)pe[0];  // t odd  -> tau even -> Re
    r[2] += (float)po[1];
    r[3] += (float)pe[1];
  }
  float4 e4 = *(const float4*)(delta + (b << 10) + tid * 4);
  float4 d4 = *(const float4*)(data + base);
  const float* e = (const float*)&e4;
  const float* d = (const float*)&d4;
  float w[4];
  int me = (b << 10) + tid * 4;
#pragma unroll
  for (int j = 0; j < 4; ++j) w[j] = mask_w(mask, bytemode, me + j);
  // pass 1: nb, data stats, f4095/f4096 fixup dots
  float nbv = 0.f, sd = 0.f, sd2 = 0.f, sdd = 0.f, sdc = 0.f;
#pragma unroll
  for (int j = 0; j < 4; ++j) {
    float wd = w[j] * d[j];
    nbv += w[j];
    sd += wd;
    sd2 += wd * d[j];
    sdd += wd * e[j];
    sdc += (j & 1) ? wd : -wd;  // (-1)^(t+1)
  }
#pragma unroll
  for (int m = 32; m; m >>= 1) {
    nbv += __shfl_xor(nbv, m, 64);
    sd += __shfl_xor(sd, m, 64);
    sd2 += __shfl_xor(sd2, m, 64);
    sdd += __shfl_xor(sdd, m, 64);
    sdc += __shfl_xor(sdc, m, 64);
  }
  __shared__ float red[4][5];
  __shared__ float bcast[3];
  if (lane == 0) {
    red[wid][0] = nbv; red[wid][1] = sd; red[wid][2] = sd2;
    red[wid][3] = sdd; red[wid][4] = sdc;
  }
  __syncthreads();
  if (tid == 0) {
    float n = red[0][0] + red[1][0] + red[2][0] + red[3][0];
    float a1 = red[0][1] + red[1][1] + red[2][1] + red[3][1];
    float a2 = red[0][2] + red[1][2] + red[2][2] + red[3][2];
    float a3 = red[0][3] + red[1][3] + red[2][3] + red[3][3];
    float a4 = red[0][4] + red[1][4] + red[2][4] + red[3][4];
    bcast[0] = a3 * invA[b];                 // ss4095
    bcast[1] = a4 / n;                       // cs4096
    float md = a1 / n;
    bcast[2] = (a2 - n * md * md) / (n - 1.f);  // vd
    red[0][0] = n;
  }
  __syncthreads();
  float ssv = bcast[0], csv = bcast[1];
  float sr = 0.f, sr2 = 0.f;
#pragma unroll
  for (int j = 0; j < 4; ++j) {
    r[j] += e[j] * ssv + ((j & 1) ? csv : -csv);  // sin4095 + cos4096 fixups
    float wr = w[j] * r[j];
    sr += wr;
    sr2 += wr * r[j];
  }
#pragma unroll
  for (int m = 32; m; m >>= 1) {
    sr += __shfl_xor(sr, m, 64);
    sr2 += __shfl_xor(sr2, m, 64);
  }
  __shared__ float red2[4][2];
  __shared__ float s_inv;
  if (lane == 0) { red2[wid][0] = sr; red2[wid][1] = sr2; }
  __syncthreads();
  if (tid == 0) {
    float a0 = red2[0][0] + red2[1][0] + red2[2][0] + red2[3][0];
    float a1 = red2[0][1] + red2[1][1] + red2[2][1] + red2[3][1];
    float n = red[0][0];
    float mr = a0 / n, vr = (a1 - n * mr * mr) / (n - 1.f);
    s_inv = sqrtf(bcast[2] / vr);
  }
  __syncthreads();
  float inv = s_inv;
  float4 o;
  ((float*)&o)[0] = (w[0] != 0.f) ? d[0] : r[0] * inv;
  ((float*)&o)[1] = (w[1] != 0.f) ? d[1] : r[1] * inv;
  ((float*)&o)[2] = (w[2] != 0.f) ? d[2] : r[2] * inv;
  ((float*)&o)[3] = (w[3] != 0.f) ? d[3] : r[3] * inv;
  *(float4*)(out + base) = o;
}

extern "C" void kernel_launch(void* const* d_in, const int* in_sizes, int n_in,
                              void* d_out, int out_size, void* d_ws, size_t ws_size,
                              hipStream_t stream) {
  const float* data = (const float*)d_in[0];
  const void* mask = d_in[1];
  float* out = (float*)d_out;
  char* ws = (char*)d_ws;

  float* invA = (float*)(ws + 16640);
  float* delta = (float*)(ws + 50176);       // 16 KB
  float4* scal = (float4*)(ws + 131072);     // 128 KB
  const size_t MB = 1ull << 20;
  short* AE = (short*)(ws + 1 * MB);         // AE 4MB @1MB, AO 4MB @5MB (contig)
  short* Be = (short*)(ws + 9 * MB);         // Be 4MB @9MB, Bo 4MB @13MB (contig)
  short* dmE = (short*)(ws + 17 * MB);       // dmE 2MB @17MB, dmO 2MB @19MB
  short* PQe = (short*)(ws + 21 * MB);       // 16MB @21MB
  short* PQo = (short*)(ws + 37 * MB);       // 16MB @37MB (PQe+8M elems)
  _Float16* Pe = (_Float16*)(ws + 53 * MB);  // 8MB used @53MB
  _Float16* Po = (_Float16*)(ws + 69 * MB);  // 8MB used @69MB (Pe+8M elems)

  // K1: build + prep + tau/scal + dm split (mask-mode detect decentralized)
  k_pre<<<8196, 256, 0, stream>>>(mask, data, AE, Be, dmE, scal, delta, invA);
  // GEMM1 dual: U,V (M=2048,N=4096,K=512 each), butterfly+PQ fused epilogue
  k_gemm1_pq<<<512, 512, 0, stream>>>(dmE, AE, scal, PQe, PQo);
  // GEMM2: Re/Ro (M=2048,N=512,K=4096) x2, split-K=4, fp16 partials
  k_gemm2<<<512, 512, 0, stream>>>(PQe, Be, Pe);
  // K-tail: reduce partials + fixups + stats + final select
  k_tail<<<2048, 256, 0, stream>>>(Pe, Po, data, mask, delta, invA, out);
}

// Round 11
// 88.275 us; speedup vs baseline: 1.0433x; 1.0433x over previous
//
#include <hip/hip_runtime.h>
#include <hip/hip_bf16.h>
#include <hip/hip_fp16.h>

using bf16 = __hip_bfloat16;
typedef __attribute__((ext_vector_type(8))) short bf16x8;
typedef __attribute__((ext_vector_type(4))) short short4v;
typedef __attribute__((ext_vector_type(2))) short short2v;
typedef __attribute__((ext_vector_type(4))) float f32x4;
typedef __attribute__((ext_vector_type(2))) _Float16 halfx2;

#define C_2PI_8192 7.6699039394282072e-4f

static __device__ __forceinline__ short bf16bits(float v) {
  bf16 h = __float2bfloat16(v);
  return *reinterpret_cast<short*>(&h);
}

#define GLOAD(gp, lp)                                                          \
  __builtin_amdgcn_global_load_lds(                                            \
      (const __attribute__((address_space(1))) void*)(gp),                     \
      (__attribute__((address_space(3))) void*)(lp), 16, 0, 0)

// Decentralized mask-mode detect: byte-bools ~75% nonzero vs int32 ~18.75%.
#define DETECT_BYTEMODE(mask, tid, outvar)                                     \
  __shared__ int _cnt;                                                         \
  if ((tid) == 0) _cnt = 0;                                                    \
  __syncthreads();                                                             \
  {                                                                            \
    const unsigned char* _mb = (const unsigned char*)(mask);                   \
    int _c = 0;                                                                \
    _Pragma("unroll")                                                          \
    for (int _i = 0; _i < 16; ++_i) _c += (_mb[(tid) * 16 + _i] != 0) ? 1 : 0; \
    atomicAdd(&_cnt, _c);                                                      \
  }                                                                            \
  __syncthreads();                                                             \
  const bool outvar = (_cnt > 2048);

static __device__ __forceinline__ float mask_w(const void* mask, bool bytemode, int e) {
  if (bytemode) return (((const unsigned char*)mask)[e] != 0) ? 1.f : 0.f;
  return (((const int*)mask)[e] != 0) ? 1.f : 0.f;
}

// ---------------- K1: build basis tables + f=4095 replica prep + tau/scal + dm
// blocks [0,4096): basis build; [4096,4100): per-b f32-replica (delta, invA);
// [4100,6148): tau/scal (m in [1,2048]); [6148,8196): dm even/odd split.
__global__ __launch_bounds__(256) void k_pre(const void* __restrict__ mask,
                                             const float* __restrict__ data,
                                             bf16* __restrict__ AE,
                                             bf16* __restrict__ Be,
                                             bf16* __restrict__ dmE,
                                             float4* __restrict__ scal,
                                             float* __restrict__ delta,
                                             float* __restrict__ invA) {
  int bid = blockIdx.x, tid = threadIdx.x;
  if (bid < 4096) {
    // ---- basis build (rotation recurrence: 2 trans + 7 rotations) ----
    int region = bid >> 10;
    int idx = (bid & 1023) * 256 + tid;
    short4v lo, hi;
    if (region < 2) {
      // AE/AO: [4096][512], row r: m=(r&2047)+1, sin if r<2048; tau=2(j+1) / 2j+1
      int r = idx >> 6, j8 = (idx & 63) << 3;
      int m = (r & 2047) + 1;
      bool is_sin = (r < 2048);
      int ph0 = (region == 0) ? ((m * (2 * j8 + 2)) & 8191) : ((m * (2 * j8 + 1)) & 8191);
      int step = (2 * m) & 8191;
      float s = __sinf(ph0 * C_2PI_8192), c = __cosf(ph0 * C_2PI_8192);
      float sr = __sinf(step * C_2PI_8192), cr = __cosf(step * C_2PI_8192);
#pragma unroll
      for (int j = 0; j < 8; ++j) {
        float v = is_sin ? s : c;
        if (j < 4) lo[j] = bf16bits(v); else hi[j - 4] = bf16bits(v);
        float ns = s * cr + c * sr;
        c = c * cr - s * sr;
        s = ns;
      }
      short* dst = (short*)AE + (size_t)region * 2097152 + ((size_t)r << 9) + j8;
      *(short4v*)dst = lo;
      *(short4v*)(dst + 4) = hi;
    } else {
      // Be/Bo: [512][4096], row j: tau=2j+2 / 2j+1
      int jr = idx >> 9, k8 = (idx & 511) << 3;
      int tau = (region == 2) ? (2 * jr + 2) : (2 * jr + 1);
      int m0 = (k8 & 2047) + 1;
      bool is_sin = (k8 < 2048);
      int ph0 = (m0 * tau) & 8191;
      float s = __sinf(ph0 * C_2PI_8192), c = __cosf(ph0 * C_2PI_8192);
      float sr = __sinf(tau * C_2PI_8192), cr = __cosf(tau * C_2PI_8192);
#pragma unroll
      for (int j = 0; j < 8; ++j) {
        float v = is_sin ? s : c;
        if (j < 4) lo[j] = bf16bits(v); else hi[j - 4] = bf16bits(v);
        float ns = s * cr + c * sr;
        c = c * cr - s * sr;
        s = ns;
      }
      short* dst = (short*)Be + (size_t)(region - 2) * 2097152 + ((size_t)jr << 12) + k8;
      *(short4v*)dst = lo;
      *(short4v*)(dst + 4) = hi;
    }
    return;
  }
  DETECT_BYTEMODE(mask, tid, bytemode)
  int wid = tid >> 6, lane = tid & 63;
  if (bid < 4100) {
    // ---- f=4095 (m=4096) sin replica: reference f32 arithmetic (accurate sinf!)
    int b = bid - 4096;
    int base_b = b << 10;
    const float W = (float)(6.283185307179586 / 8192.0);
    const float ang = W * 4096.0f;
    __shared__ float red[4][2];
    __shared__ float bc2[1];
    float num = 0.f, den = 0.f;
    for (int t = tid; t < 1024; t += 256) {
      float arg = ang * (float)(t + 1);
      float w = mask_w(mask, bytemode, base_b + t);
      num += w * sinf(2.0f * arg);
      den += w * cosf(2.0f * arg);
    }
#pragma unroll
    for (int m = 32; m; m >>= 1) {
      num += __shfl_xor(num, m, 64);
      den += __shfl_xor(den, m, 64);
    }
    if (lane == 0) { red[wid][0] = num; red[wid][1] = den; }
    __syncthreads();
    if (tid == 0) {
      float a0 = red[0][0] + red[1][0] + red[2][0] + red[3][0];
      float a1 = red[0][1] + red[1][1] + red[2][1] + red[3][1];
      float tau = atan2f(a0, a1) / (2.0f * ang);
      bc2[0] = ang * tau;
    }
    __syncthreads();
    float P = bc2[0];
    float dss = 0.f;
    for (int t = tid; t < 1024; t += 256) {
      float arg = ang * (float)(t + 1);
      float d = sinf(arg - P);
      delta[base_b + t] = d;
      float w = mask_w(mask, bytemode, base_b + t);
      dss += w * d * d;
    }
#pragma unroll
    for (int m = 32; m; m >>= 1) dss += __shfl_xor(dss, m, 64);
    if (lane == 0) red[wid][0] = dss;
    __syncthreads();
    if (tid == 0)
      invA[b] = 1.f / (red[0][0] + red[1][0] + red[2][0] + red[3][0]);
  } else if (bid < 6148) {
    // ---- tau/scal for m in [1,2048]: one wave per (b,f), rotation recurrence ----
    int gw = (bid - 4100) * 4 + wid;
    int b = gw >> 11, f = gw & 2047;
    int base_b = b << 10;
    float num = 0.f, den = 0.f, nb = 0.f;
    int f2 = 2 * (f + 1);
    {
      int ph0 = (f2 * (lane + 1)) & 8191;
      int st = (f2 << 6) & 8191;
      float s = __sinf(ph0 * C_2PI_8192), c = __cosf(ph0 * C_2PI_8192);
      float sr = __sinf(st * C_2PI_8192), cr = __cosf(st * C_2PI_8192);
#pragma unroll
      for (int i = 0; i < 16; ++i) {
        float w = mask_w(mask, bytemode, base_b + lane + (i << 6));
        num += w * s;
        den += w * c;
        nb += w;
        float ns = s * cr + c * sr;
        c = c * cr - s * sr;
        s = ns;
      }
    }
#pragma unroll
    for (int m = 32; m; m >>= 1) {
      num += __shfl_xor(num, m, 64);
      den += __shfl_xor(den, m, 64);
      nb += __shfl_xor(nb, m, 64);
    }
    if (lane == 0) {
      float th = 0.5f * atan2f(num, den);
      float c = cosf(th), s = sinf(th);
      float WSS = 0.5f * (nb - den);
      float WCC = 0.5f * (nb + den);
      float WSC = 0.5f * num;
      float den_s = c * c * WSS - 2.f * c * s * WSC + s * s * WCC;
      float den_c = c * c * WCC + 2.f * c * s * WSC + s * s * WSS;
      scal[gw] = make_float4(c, s, 1.f / den_s, 1.f / den_c);
    }
  } else {
    // ---- dm even/odd-tau split ----
    int bc = bid - 6148, b = bc >> 9;
    bf16* dmO = dmE + (1 << 20);
    size_t base = (size_t)bc * 1024 + tid * 4;
    float4 d4 = *(const float4*)(data + base);
    const float* d = (const float*)&d4;
    int me = (b << 10) + tid * 4;
    float wd[4];
#pragma unroll
    for (int j = 0; j < 4; ++j) wd[j] = mask_w(mask, bytemode, me + j) * d[j];
    // t even -> tau odd -> dmO[t/2]; t odd -> tau even -> dmE[(t-1)/2]
    short2v dE, dO;
    dO[0] = bf16bits(wd[0]); dE[0] = bf16bits(wd[1]);
    dO[1] = bf16bits(wd[2]); dE[1] = bf16bits(wd[3]);
    *(short2v*)((short*)dmE + (size_t)bc * 512 + tid * 2) = dE;
    *(short2v*)((short*)dmO + (size_t)bc * 512 + tid * 2) = dO;
  }
}

// ---------------- GEMM1 dual (U=even-tau, V=odd-tau) + butterfly-PQ epilogue --
// 512 threads, 8 waves (2M x 4N), per-wave 64x32 output, acc[4][2] x2.
__global__ __launch_bounds__(512, 4) void k_gemm1_pq(const bf16* __restrict__ dmE,
                                                     const bf16* __restrict__ AE,
                                                     const float4* __restrict__ scal,
                                                     bf16* __restrict__ PQe,
                                                     bf16* __restrict__ PQo) {
  __shared__ bf16 As[128 * 64];
  __shared__ bf16 Bs[128 * 64];
  int bid = blockIdx.x;
  int swz = ((bid & 7) << 6) | (bid >> 3);  // 512 blocks, bijective
  int mt = swz & 15, ft = swz >> 4;          // ft in [0,32)
  int m0 = mt << 7, f0 = ft << 6;
  int tid = threadIdx.x, lane = tid & 63, wid = tid >> 6;
  int wm = (wid >> 2) << 6, wn = (wid & 3) << 5;
  int fr = lane & 15, kh = lane >> 4;

  int r0 = tid >> 3;                          // rows 0-63 per GLOAD wave-set
  int scol = ((tid & 7) ^ (r0 & 7)) << 3;
  const bf16* pa0 = dmE + (size_t)(m0 + r0) * 512 + scol;
  const bf16* pb0;
  const bf16* pb1;
  {
    int row0 = r0, row1 = 64 + r0;
    int g0 = ((row0 >> 4) & 1) * 2048 + f0 + (row0 & 15) + ((row0 >> 5) << 4);
    int g1 = ((row1 >> 4) & 1) * 2048 + f0 + (row1 & 15) + ((row1 >> 5) << 4);
    pb0 = AE + (size_t)g0 * 512 + scol;
    pb1 = AE + (size_t)g1 * 512 + scol;
  }
  char* lA = (char*)As + (wid << 10);
  char* lB = (char*)Bs + (wid << 10);

  f32x4 accU[4][2] = {};
  f32x4 accV[4][2] = {};
  int sw = fr & 7;

#define K_BODY(ACC)                                                              \
  for (int kt = 0; kt < 8; ++kt) {                                               \
    GLOAD(pa0, lA);                                                              \
    GLOAD(pa0 + 32768, lA + 8192);                                               \
    GLOAD(pb0, lB);                                                              \
    GLOAD(pb1, lB + 8192);                                                       \
    pa0 += 64; pb0 += 64; pb1 += 64;                                             \
    __syncthreads();                                                             \
    _Pragma("unroll")                                                            \
    for (int s = 0; s < 2; ++s) {                                                \
      bf16x8 a[4];                                                               \
      _Pragma("unroll")                                                          \
      for (int i = 0; i < 4; ++i)                                                \
        a[i] = *(const bf16x8*)&As[(wm + i * 16 + fr) * 64 + ((((s << 2) + kh) ^ sw) << 3)]; \
      _Pragma("unroll")                                                          \
      for (int j = 0; j < 2; ++j) {                                              \
        bf16x8 bb = *(const bf16x8*)&Bs[(wn + j * 16 + fr) * 64 + ((((s << 2) + kh) ^ sw) << 3)]; \
        _Pragma("unroll")                                                        \
        for (int i = 0; i < 4; ++i)                                              \
          ACC[i][j] = __builtin_amdgcn_mfma_f32_16x16x32_bf16(a[i], bb, ACC[i][j], 0, 0, 0); \
      }                                                                          \
    }                                                                            \
    __syncthreads();                                                             \
  }

  K_BODY(accU)
  pa0 += (1 << 20) - 512;                    // dmO = dmE + 1M elems
  pb0 += (2 << 20) - 512;                    // AO = AE + 2M elems
  pb1 += (2 << 20) - 512;
  K_BODY(accV)
#undef K_BODY

  int b = m0 >> 9;
  short* pqe = (short*)PQe;
  short* pqo = (short*)PQo;
  {
    int f = f0 + (wn >> 1) + fr;             // 16 f's per wave
    float4 sc = scal[(b << 11) + f];
    float c = sc.x, s = sc.y, ids = sc.z, idc = sc.w;
    bool self = (f == 2047);                 // m=2048 pairs with itself
#pragma unroll
    for (int i = 0; i < 4; ++i) {
#pragma unroll
      for (int q = 0; q < 4; ++q) {
        int bc = m0 + wm + i * 16 + (kh << 2) + q;
        float US = accU[i][0][q], UC = accU[i][1][q];
        float VS = accV[i][0][q], VC = accV[i][1][q];
        float Gs = US + VS, Gc = UC + VC;      // freq m
        float gs = VS - US, gc = UC - VC;      // freq 4096-m
        float ss = (c * Gs - s * Gc) * ids;
        float cs = (c * Gc + s * Gs) * idc;
        float P = c * ss + s * cs;
        float Q = c * cs - s * ss;
        float ssp = (c * gs + s * gc) * ids;   // partner scal: (c,-s,ids,idc)
        float csp = (c * gc - s * gs) * idc;
        float Pp = self ? 0.f : (c * ssp - s * csp);
        float Qp = self ? 0.f : (c * csp + s * ssp);
        size_t base = (size_t)bc * 4096 + f;
        pqe[base] = bf16bits(P - Pp);
        pqe[base + 2048] = bf16bits(Q + Qp);
        pqo[base] = bf16bits(P + Pp);
        pqo[base + 2048] = bf16bits(Q - Qp);
      }
    }
  }
}

// ---------------- GEMM2 (NT, eo x split-K=4, fp16 partials), 512 threads ------
__global__ __launch_bounds__(512, 4) void k_gemm2(const bf16* __restrict__ PQe,
                                                  const bf16* __restrict__ Be,
                                                  _Float16* __restrict__ Pe) {
  __shared__ bf16 As[128 * 64];
  __shared__ bf16 Bs[128 * 64];
  int bid = blockIdx.x;
  int swz = ((bid & 7) << 6) | (bid >> 3);  // 512 blocks, bijective
  int eo = swz >> 8;
  int slice = (swz >> 6) & 3;
  int tl = swz & 63;
  int mt = tl & 15, nt = tl >> 4;
  int m0 = mt << 7, n0 = nt << 7;
  int tid = threadIdx.x, lane = tid & 63, wid = tid >> 6;
  int wm = (wid >> 2) << 6, wn = (wid & 3) << 5;
  int fr = lane & 15, kh = lane >> 4;

  const bf16* A = PQe + (size_t)eo * (8 << 20);
  const bf16* B = Be + (size_t)eo * (2 << 20);
  _Float16* C = Pe + (size_t)eo * (8 << 20);

  int r0 = tid >> 3;
  int scol = ((tid & 7) ^ (r0 & 7)) << 3;
  const bf16* pa0 = A + (size_t)slice * 1024 + (size_t)(m0 + r0) * 4096 + scol;
  const bf16* pb0 = B + (size_t)slice * 1024 + (size_t)(n0 + r0) * 4096 + scol;
  _Float16* Cp = C + (size_t)slice * 1048576;
  char* lA = (char*)As + (wid << 10);
  char* lB = (char*)Bs + (wid << 10);

  f32x4 acc[4][2] = {};
  int sw = fr & 7;

  for (int kt = 0; kt < 16; ++kt) {
    GLOAD(pa0, lA);
    GLOAD(pa0 + 262144, lA + 8192);
    GLOAD(pb0, lB);
    GLOAD(pb0 + 262144, lB + 8192);
    pa0 += 64; pb0 += 64;
    __syncthreads();
#pragma unroll
    for (int s = 0; s < 2; ++s) {
      bf16x8 a[4];
#pragma unroll
      for (int i = 0; i < 4; ++i)
        a[i] = *(const bf16x8*)&As[(wm + i * 16 + fr) * 64 + ((((s << 2) + kh) ^ sw) << 3)];
#pragma unroll
      for (int j = 0; j < 2; ++j) {
        bf16x8 bb = *(const bf16x8*)&Bs[(wn + j * 16 + fr) * 64 + ((((s << 2) + kh) ^ sw) << 3)];
#pragma unroll
        for (int i = 0; i < 4; ++i)
          acc[i][j] = __builtin_amdgcn_mfma_f32_16x16x32_bf16(a[i], bb, acc[i][j], 0, 0, 0);
      }
    }
    __syncthreads();
  }
#pragma unroll
  for (int i = 0; i < 4; ++i) {
#pragma unroll
    for (int q = 0; q < 4; ++q) {
      size_t row = m0 + wm + i * 16 + (kh << 2) + q;
      _Float16* cp = Cp + row * 512 + n0 + wn + fr;
#pragma unroll
      for (int j = 0; j < 2; ++j) cp[j * 16] = (_Float16)acc[i][j][q];
    }
  }
}

// ---------------- K-tail: merge partials + all per-bc stats + final select ----
__global__ __launch_bounds__(256) void k_tail(const _Float16* __restrict__ Pe,
                                              const _Float16* __restrict__ Po,
                                              const float* __restrict__ data,
                                              const void* __restrict__ mask,
                                              const float* __restrict__ delta,
                                              const float* __restrict__ invA,
                                              float* __restrict__ out) {
  int bc = blockIdx.x, b = bc >> 9, tid = threadIdx.x;
  DETECT_BYTEMODE(mask, tid, bytemode)
  int wid = tid >> 6, lane = tid & 63;
  size_t base = (size_t)bc * 1024 + tid * 4;
  int jj = tid * 2;
  float r[4] = {0.f, 0.f, 0.f, 0.f};
#pragma unroll
  for (int s = 0; s < 4; ++s) {
    halfx2 pe = *(const halfx2*)(Pe + (size_t)s * 1048576 + (size_t)bc * 512 + jj);
    halfx2 po = *(const halfx2*)(Po + (size_t)s * 1048576 + (size_t)bc * 512 + jj);
    r[0] += (float)po[0];  // t even -> tau odd -> Ro
    r[1] += (float)pe[0];  // t odd  -> tau even -> Re
    r[2] += (float)po[1];
    r[3] += (float)pe[1];
  }
  float4 e4 = *(const float4*)(delta + (b << 10) + tid * 4);
  float4 d4 = *(const float4*)(data + base);
  const float* e = (const float*)&e4;
  const float* d = (const float*)&d4;
  float w[4];
  int me = (b << 10) + tid * 4;
#pragma unroll
  for (int j = 0; j < 4; ++j) w[j] = mask_w(mask, bytemode, me + j);
  // pass 1: nb, data stats, f4095/f4096 fixup dots
  float nbv = 0.f, sd = 0.f, sd2 = 0.f, sdd = 0.f, sdc = 0.f;
#pragma unroll
  for (int j = 0; j < 4; ++j) {
    float wd = w[j] * d[j];
    nbv += w[j];
    sd += wd;
    sd2 += wd * d[j];
    sdd += wd * e[j];
    sdc += (j & 1) ? wd : -wd;  // (-1)^(t+1)
  }
#pragma unroll
  for (int m = 32; m; m >>= 1) {
    nbv += __shfl_xor(nbv, m, 64);
    sd += __shfl_xor(sd, m, 64);
    sd2 += __shfl_xor(sd2, m, 64);
    sdd += __shfl_xor(sdd, m, 64);
    sdc += __shfl_xor(sdc, m, 64);
  }
  __shared__ float red[4][5];
  __shared__ float bcast[3];
  if (lane == 0) {
    red[wid][0] = nbv; red[wid][1] = sd; red[wid][2] = sd2;
    red[wid][3] = sdd; red[wid][4] = sdc;
  }
  __syncthreads();
  if (tid == 0) {
    float n = red[0][0] + red[1][0] + red[2][0] + red[3][0];
    float a1 = red[0][1] + red[1][1] + red[2][1] + red[3][1];
    float a2 = red[0][2] + red[1][2] + red[2][2] + red[3][2];
    float a3 = red[0][3] + red[1][3] + red[2][3] + red[3][3];
    float a4 = red[0][4] + red[1][4] + red[2][4] + red[3][4];
    bcast[0] = a3 * invA[b];                 // ss4095
    bcast[1] = a4 / n;                       // cs4096
    float md = a1 / n;
    bcast[2] = (a2 - n * md * md) / (n - 1.f);  // vd
    red[0][0] = n;
  }
  __syncthreads();
  float ssv = bcast[0], csv = bcast[1];
  float sr = 0.f, sr2 = 0.f;
#pragma unroll
  for (int j = 0; j < 4; ++j) {
    r[j] += e[j] * ssv + ((j & 1) ? csv : -csv);  // sin4095 + cos4096 fixups
    float wr = w[j] * r[j];
    sr += wr;
    sr2 += wr * r[j];
  }
#pragma unroll
  for (int m = 32; m; m >>= 1) {
    sr += __shfl_xor(sr, m, 64);
    sr2 += __shfl_xor(sr2, m, 64);
  }
  __shared__ float red2[4][2];
  __shared__ float s_inv;
  if (lane == 0) { red2[wid][0] = sr; red2[wid][1] = sr2; }
  __syncthreads();
  if (tid == 0) {
    float a0 = red2[0][0] + red2[1][0] + red2[2][0] + red2[3][0];
    float a1 = red2[0][1] + red2[1][1] + red2[2][1] + red2[3][1];
    float n = red[0][0];
    float mr = a0 / n, vr = (a1 - n * mr * mr) / (n - 1.f);
    s_inv = sqrtf(bcast[2] / vr);
  }
  __syncthreads();
  float inv = s_inv;
  float4 o;
  ((float*)&o)[0] = (w[0] != 0.f) ? d[0] : r[0] * inv;
  ((float*)&o)[1] = (w[1] != 0.f) ? d[1] : r[1] * inv;
  ((float*)&o)[2] = (w[2] != 0.f) ? d[2] : r[2] * inv;
  ((float*)&o)[3] = (w[3] != 0.f) ? d[3] : r[3] * inv;
  *(float4*)(out + base) = o;
}

extern "C" void kernel_launch(void* const* d_in, const int* in_sizes, int n_in,
                              void* d_out, int out_size, void* d_ws, size_t ws_size,
                              hipStream_t stream) {
  const float* data = (const float*)d_in[0];
  const void* mask = d_in[1];
  float* out = (float*)d_out;
  char* ws = (char*)d_ws;

  float* invA = (float*)(ws + 16640);
  float* delta = (float*)(ws + 50176);       // 16 KB
  float4* scal = (float4*)(ws + 131072);     // 128 KB
  const size_t MB = 1ull << 20;
  bf16* AE = (bf16*)(ws + 1 * MB);           // AE 4MB @1MB, AO 4MB @5MB (contig)
  bf16* Be = (bf16*)(ws + 9 * MB);           // Be 4MB @9MB, Bo 4MB @13MB (contig)
  bf16* dmE = (bf16*)(ws + 17 * MB);         // dmE 2MB @17MB, dmO 2MB @19MB
  bf16* PQe = (bf16*)(ws + 21 * MB);         // 16MB @21MB
  bf16* PQo = (bf16*)(ws + 37 * MB);         // 16MB @37MB (PQe+8M elems)
  _Float16* Pe = (_Float16*)(ws + 53 * MB);  // 8MB used @53MB
  _Float16* Po = (_Float16*)(ws + 69 * MB);  // 8MB used @69MB (Pe+8M elems)

  // K1: build + prep + tau/scal + dm split (mask-mode detect decentralized)
  k_pre<<<8196, 256, 0, stream>>>(mask, data, AE, Be, dmE, scal, delta, invA);
  // GEMM1 dual: U,V (M=2048,N=4096,K=512 each), butterfly+PQ fused epilogue
  k_gemm1_pq<<<512, 512, 0, stream>>>(dmE, AE, scal, PQe, PQo);
  // GEMM2: Re/Ro (M=2048,N=512,K=4096) x2, split-K=4, fp16 partials
  k_gemm2<<<512, 512, 0, stream>>>(PQe, Be, Pe);
  // K-tail: reduce partials + fixups + stats + final select
  k_tail<<<2048, 256, 0, stream>>>(Pe, Po, data, mask, delta, invA, out);
}